// Round 10
// baseline (396.013 us; speedup 1.0000x reference)
//
#include <hip/hip_runtime.h>
#include <hip/hip_bf16.h>
#include <cstdint>
#include <cstddef>
#include <type_traits>

#define NN 30000
#define NE 480000
#define NG 128
#define DIN 128
#define DH 256
#define NC 60
#define NB 118  // scan blocks: ceil(30000/256)

typedef _Float16 f16x8 __attribute__((ext_vector_type(8)));
typedef _Float16 half4_t __attribute__((ext_vector_type(4)));
typedef _Float16 half2_t __attribute__((ext_vector_type(2)));
typedef float f32x4 __attribute__((ext_vector_type(4)));

// ---------------- fused preprocessing: edge-count + x->fp16 + W->fp16 ----------------
__global__ __launch_bounds__(256) void k_pre(const int* __restrict__ dst, int* __restrict__ icnt,
                     const float* __restrict__ x, _Float16* __restrict__ xh,
                     const float* __restrict__ W1, const float* __restrict__ W2,
                     const float* __restrict__ W3, _Float16* __restrict__ w1h,
                     _Float16* __restrict__ w2h, _Float16* __restrict__ w3h) {
    int i = blockIdx.x * 256 + threadIdx.x;
    if (i < NE) atomicAdd(&icnt[dst[i]], 1);
    if (i < NN * DIN / 4) {
        float4 v = ((const float4*)x)[i];
        half4_t o;
        o[0] = (_Float16)v.x; o[1] = (_Float16)v.y;
        o[2] = (_Float16)v.z; o[3] = (_Float16)v.w;
        ((half4_t*)xh)[i] = o;
    }
    if (i < DH * DIN) w1h[i] = (_Float16)W1[i];
    if (i < DH * DH) {
        w2h[i] = (_Float16)W2[i];
        w3h[i] = (_Float16)W3[i];
    }
}

// scan stage 1: per-block sums of icnt, fused with dinv = rsqrt(deg+1)
__global__ __launch_bounds__(256) void k_scan1(const int* __restrict__ icnt, int* __restrict__ psum,
                                               float* __restrict__ dinv) {
    __shared__ int ws[4];
    int i = blockIdx.x * 256 + threadIdx.x;
    int lane = threadIdx.x & 63, wv = threadIdx.x >> 6;
    int v = (i < NN) ? icnt[i] : 0;
    if (i < NN) dinv[i] = rsqrtf((float)(v + 1));
    #pragma unroll
    for (int off = 32; off > 0; off >>= 1) v += __shfl_down(v, off, 64);
    if (lane == 0) ws[wv] = v;
    __syncthreads();
    if (threadIdx.x == 0) psum[blockIdx.x] = ws[0] + ws[1] + ws[2] + ws[3];
}

// scan stage 2 folded into stage 3: wave 0 reduces psum[0..blockIdx) inline,
// then row_ptr = poff + exclusive-within-block.
__global__ __launch_bounds__(256) void k_scan3(const int* __restrict__ icnt, const int* __restrict__ psum,
                                               int* __restrict__ row_ptr) {
    __shared__ int ws[4];
    __shared__ int poff_s;
    int b = blockIdx.x;
    if (threadIdx.x < 64) {
        int val = 0;
        for (int j = threadIdx.x; j < b; j += 64) val += psum[j];
        #pragma unroll
        for (int off = 32; off > 0; off >>= 1) val += __shfl_down(val, off, 64);
        if (threadIdx.x == 0) poff_s = val;
    }
    int i = b * 256 + threadIdx.x;
    int lane = threadIdx.x & 63, wv = threadIdx.x >> 6;
    int v = (i < NN) ? icnt[i] : 0;
    int s = v;
    #pragma unroll
    for (int off = 1; off < 64; off <<= 1) {
        int n = __shfl_up(s, off, 64);
        if (lane >= off) s += n;
    }
    if (lane == 63) ws[wv] = s;
    __syncthreads();
    int add = 0;
    for (int j = 0; j < wv; j++) add += ws[j];
    if (i < NN) row_ptr[i] = poff_s + add + s - v;
    if (b == 0 && threadIdx.x == 0) row_ptr[NN] = NE;
}

__global__ void k_fill(const int* __restrict__ ei, const float* __restrict__ dinv,
                       const int* __restrict__ row_ptr, int* __restrict__ cursor,
                       int* __restrict__ csr_src, float* __restrict__ csr_w) {
    int e = blockIdx.x * blockDim.x + threadIdx.x;
    if (e >= NE) return;
    int s = ei[e];        // edge_index[0]
    int d = ei[NE + e];   // edge_index[1]
    int pos = row_ptr[d] + atomicAdd(&cursor[d], 1);
    csr_src[pos] = s;
    csr_w[pos] = dinv[s] * dinv[d];
}

// ---------------- fused layer: agg (gather) -> LDS -> MFMA GEMM -> relu fp16 ----------------
// Block = 64 output rows (nodes). Phase 1: wave wv aggregates nodes bm+16wv..+15
//   u[v] = sum_e w_e*hin[src_e] + dinv[v]^2*hin[v]  (fp32 acc, fp16 into LDS; identical
//   rounding points to the previous separate agg kernel).
// Phase 2 (after 1 barrier): wave wv computes C rows bm..bm+63 x cols 64wv..64wv+63
//   (4x4 of 16x16x32 f16 MFMA); A fragments from LDS (stride K+4 halves: max 4-way bank
//   alias), B fragments streamed from the 128 KB L2-hot W — no staging, no K-loop barriers.
template<int K>
__global__ __launch_bounds__(256, 4) void k_layer(const _Float16* __restrict__ hin,
        const _Float16* __restrict__ W, const float* __restrict__ bias,
        _Float16* __restrict__ hout,
        const int* __restrict__ row_ptr, const int* __restrict__ csr_src,
        const float* __restrict__ csr_w, const float* __restrict__ dinv) {
    constexpr int V = K / 64;
    constexpr int LS = K + 4;  // LDS row stride in halves
    using vec_t = std::conditional_t<V == 4, half4_t, half2_t>;
    __shared__ _Float16 lsA[64 * LS];
    int t = threadIdx.x;
    int lane = t & 63, wv = t >> 6;
    int bm = blockIdx.x * 64;
    const _Float16* gbase = hin + lane * V;

    // ---- phase 1: aggregate 16 nodes per wave into LDS ----
    for (int i = 0; i < 16; i++) {
        int nl = wv * 16 + i;
        int node = bm + nl;
        float acc[V];
        #pragma unroll
        for (int u = 0; u < V; u++) acc[u] = 0.f;
        if (node < NN) {
            int beg = row_ptr[node], end = row_ptr[node + 1];
            int e = beg;
            for (; e + 16 <= end; e += 16) {
                int s[16]; float w[16];
                #pragma unroll
                for (int j = 0; j < 16; j++) { s[j] = csr_src[e + j]; w[j] = csr_w[e + j]; }
                vec_t r[16];
                #pragma unroll
                for (int j = 0; j < 16; j++) r[j] = *(const vec_t*)(gbase + (size_t)s[j] * K);
                #pragma unroll
                for (int j = 0; j < 16; j++)
                    #pragma unroll
                    for (int u = 0; u < V; u++) acc[u] = fmaf(w[j], (float)r[j][u], acc[u]);
            }
            for (; e + 8 <= end; e += 8) {
                int s[8]; float w[8];
                #pragma unroll
                for (int j = 0; j < 8; j++) { s[j] = csr_src[e + j]; w[j] = csr_w[e + j]; }
                vec_t r[8];
                #pragma unroll
                for (int j = 0; j < 8; j++) r[j] = *(const vec_t*)(gbase + (size_t)s[j] * K);
                #pragma unroll
                for (int j = 0; j < 8; j++)
                    #pragma unroll
                    for (int u = 0; u < V; u++) acc[u] = fmaf(w[j], (float)r[j][u], acc[u]);
            }
            for (; e < end; e++) {
                int s0 = csr_src[e];
                float w0 = csr_w[e];
                vec_t r0 = *(const vec_t*)(gbase + (size_t)s0 * K);
                #pragma unroll
                for (int u = 0; u < V; u++) acc[u] = fmaf(w0, (float)r0[u], acc[u]);
            }
            float dv = dinv[node];
            float sw = dv * dv;
            vec_t rv = *(const vec_t*)(gbase + (size_t)node * K);
            #pragma unroll
            for (int u = 0; u < V; u++) acc[u] = fmaf(sw, (float)rv[u], acc[u]);
        }
        vec_t o;
        #pragma unroll
        for (int u = 0; u < V; u++) o[u] = (_Float16)acc[u];
        *(vec_t*)&lsA[nl * LS + lane * V] = o;
    }
    __syncthreads();

    // ---- phase 2: GEMM, wave tile 64 rows x 64 cols ----
    int lm = lane & 15, q = lane >> 4;
    int wn = wv * 64;
    f32x4 acc[4][4];
    #pragma unroll
    for (int i = 0; i < 4; i++)
        #pragma unroll
        for (int j = 0; j < 4; j++) acc[i][j] = (f32x4){0.f, 0.f, 0.f, 0.f};
    #pragma unroll
    for (int kt = 0; kt < K / 32; kt++) {
        f16x8 bf[4];
        #pragma unroll
        for (int nt = 0; nt < 4; nt++)
            bf[nt] = *(const f16x8*)(W + (size_t)(wn + nt * 16 + lm) * K + kt * 32 + q * 8);
        #pragma unroll
        for (int mt = 0; mt < 4; mt++) {
            f16x8 af = *(const f16x8*)&lsA[(mt * 16 + lm) * LS + kt * 32 + q * 8];
            #pragma unroll
            for (int nt = 0; nt < 4; nt++)
                acc[mt][nt] = __builtin_amdgcn_mfma_f32_16x16x32_f16(af, bf[nt], acc[mt][nt], 0, 0, 0);
        }
    }
    // epilogue: C/D layout col = lane&15, row = q*4 + r
    #pragma unroll
    for (int mt = 0; mt < 4; mt++) {
        #pragma unroll
        for (int nt = 0; nt < 4; nt++) {
            int col = wn + nt * 16 + lm;
            float bv = bias[col];
            #pragma unroll
            for (int r = 0; r < 4; r++) {
                int row = bm + mt * 16 + q * 4 + r;
                if (row < NN) {
                    float v = fmaxf(acc[mt][nt][r] + bv, 0.f);
                    hout[(size_t)row * 256 + col] = (_Float16)v;
                }
            }
        }
    }
}

// ---------------- pool stage 1: chunked segmented sum (batch sorted), fp16 in ----------------
__global__ __launch_bounds__(256) void k_pool(const _Float16* __restrict__ h, const int* __restrict__ batch,
                       float* __restrict__ sums) {
    int f = threadIdx.x;
    int r0 = blockIdx.x * 64;
    int r1 = min(r0 + 64, NN);
    float acc = 0.f;
    int cur = batch[r0];
    for (int r = r0; r < r1; r++) {
        int g = batch[r];  // uniform across block; L1 broadcast
        if (g != cur) {
            atomicAdd(&sums[cur * DH + f], acc);
            acc = 0.f;
            cur = g;
        }
        acc += (float)h[(size_t)r * DH + f];
    }
    atomicAdd(&sums[cur * DH + f], acc);
}

// ---------------- FC: out[G x 60] = (sums[g]/cnt) @ Wfc[60 x 256]^T + bfc ----------------
__global__ __launch_bounds__(64) void k_fc(const float* __restrict__ sums, const int* __restrict__ batch,
                    const float* __restrict__ Wfc, const float* __restrict__ bfc,
                    float* __restrict__ out) {
    __shared__ float p[DH];
    int g = blockIdx.x;
    int t = threadIdx.x;
    // count rows of graph g (batch sorted): redundant binary search per thread
    int lo = 0, hi = NN;
    while (lo < hi) { int mid = (lo + hi) >> 1; if (batch[mid] < g) lo = mid + 1; else hi = mid; }
    int start = lo;
    hi = NN;
    while (lo < hi) { int mid = (lo + hi) >> 1; if (batch[mid] < g + 1) lo = mid + 1; else hi = mid; }
    int cnt = lo - start;
    float inv = (cnt > 0) ? 1.f / (float)cnt : 0.f;
    for (int i = t; i < DH; i += 64) p[i] = sums[g * DH + i] * inv;
    __syncthreads();
    if (t < NC) {
        float a = bfc[t];
        for (int k = 0; k < DH; k++) a = fmaf(p[k], Wfc[t * DH + k], a);
        out[g * NC + t] = a;
    }
}

extern "C" void kernel_launch(void* const* d_in, const int* in_sizes, int n_in,
                              void* d_out, int out_size, void* d_ws, size_t ws_size,
                              hipStream_t stream) {
    const float* x     = (const float*)d_in[0];
    const int*   ei    = (const int*)d_in[1];
    const int*   batch = (const int*)d_in[2];
    const float* W1 = (const float*)d_in[3];
    const float* b1 = (const float*)d_in[4];
    const float* W2 = (const float*)d_in[5];
    const float* b2 = (const float*)d_in[6];
    const float* W3 = (const float*)d_in[7];
    const float* b3 = (const float*)d_in[8];
    const float* Wfc = (const float*)d_in[9];
    const float* bfc = (const float*)d_in[10];
    float* out = (float*)d_out;

    char* wp = (char*)d_ws;
    auto alloc = [&](size_t bytes) {
        char* p = wp;
        wp += (bytes + 511) & ~(size_t)511;
        return (void*)p;
    };
    // zero zone: icnt | cursor | sums contiguous -> one memset
    int*   icnt    = (int*)alloc((size_t)NN * 4);
    int*   cursor  = (int*)alloc((size_t)NN * 4);
    float* sums    = (float*)alloc((size_t)NG * DH * 4);
    size_t zlen = (char*)wp - (char*)icnt;
    int*   row_ptr = (int*)alloc((size_t)(NN + 1) * 4);
    int*   psum    = (int*)alloc((size_t)NB * 4);
    int*   csr_src = (int*)alloc((size_t)NE * 4);
    float* csr_w   = (float*)alloc((size_t)NE * 4);
    float* dinv    = (float*)alloc((size_t)NN * 4);
    _Float16* xh   = (_Float16*)alloc((size_t)NN * DIN * 2);
    _Float16* hA   = (_Float16*)alloc((size_t)NN * DH * 2);
    _Float16* hB   = (_Float16*)alloc((size_t)NN * DH * 2);
    _Float16* w1h = (_Float16*)alloc((size_t)DH * DIN * 2);
    _Float16* w2h = (_Float16*)alloc((size_t)DH * DH * 2);
    _Float16* w3h = (_Float16*)alloc((size_t)DH * DH * 2);

    hipMemsetAsync(icnt, 0, zlen, stream);

    // fused: edge degree count + x->fp16 + all W->fp16 (grid covers the max job)
    k_pre<<<(NN * DIN / 4 + 255) / 256, 256, 0, stream>>>(ei + NE, icnt, x, xh,
                                                          W1, W2, W3, w1h, w2h, w3h);
    k_scan1<<<NB, 256, 0, stream>>>(icnt, psum, dinv);
    k_scan3<<<NB, 256, 0, stream>>>(icnt, psum, row_ptr);
    k_fill<<<(NE + 255) / 256, 256, 0, stream>>>(ei, dinv, row_ptr, cursor, csr_src, csr_w);

    int lgrid = (NN + 63) / 64;
    // h_l = relu((A.h_{l-1}) W^T + b)  [linearity reorder], fused agg+GEMM per layer
    k_layer<128><<<lgrid, 256, 0, stream>>>(xh, w1h, b1, hA, row_ptr, csr_src, csr_w, dinv);
    k_layer<256><<<lgrid, 256, 0, stream>>>(hA, w2h, b2, hB, row_ptr, csr_src, csr_w, dinv);
    k_layer<256><<<lgrid, 256, 0, stream>>>(hB, w3h, b3, hA, row_ptr, csr_src, csr_w, dinv);

    k_pool<<<(NN + 63) / 64, 256, 0, stream>>>(hA, batch, sums);
    k_fc<<<NG, 64, 0, stream>>>(sums, batch, Wfc, bfc, out);
}